// Round 13
// baseline (320.427 us; speedup 1.0000x reference)
//
#include <hip/hip_runtime.h>
#include <math.h>

#define BLK 256
// bucketed CSR build: 256 dst-nodes per bucket
#define BKT_BITS 8
#define BKT (1<<BKT_BITS)
#define NBMAX 512
#define EB 2048       // edges per bin-block
#define BSTRIDE 8192  // per-bucket slot stride in bins (mean fill 4092, 64-sigma safe)

typedef __attribute__((ext_vector_type(8))) short bf16x8;
typedef __attribute__((ext_vector_type(4))) float f32x4;

__device__ inline unsigned short f2b(float f){
  union { float f; unsigned int u; } v; v.f = f;
  unsigned int u = v.u;
  return (unsigned short)((u + 0x7FFF + ((u >> 16) & 1)) >> 16);
}
__device__ inline float b2f_lo(unsigned int u){
  union { unsigned int u; float f; } v; v.u = u << 16; return v.f;
}
__device__ inline float b2f_hi(unsigned int u){
  union { unsigned int u; float f; } v; v.u = u & 0xFFFF0000u; return v.f;
}
// packed 2xbf16 convert (RNE, same rounding as f2b) — 1 instr per 2 floats
__device__ inline unsigned pkbf(float lo, float hi){
  unsigned r;
  asm("v_cvt_pk_bf16_f32 %0, %1, %2" : "=v"(r) : "v"(lo), "v"(hi));
  return r;
}

// ---------------- K1: binC (edge bucketing) || W1 transpose/cvt ----------------

__global__ __launch_bounds__(256)
void binc_wcvt(const int* __restrict__ src, const int* __restrict__ dst,
               int* __restrict__ bcnt, unsigned int* __restrict__ bins,
               const float* __restrict__ W1, unsigned short* __restrict__ W1T,
               int E, int NCB){
  __shared__ int lh[NBMAX];
  __shared__ int lofs[NBMAX];
  __shared__ int lcur[NBMAX];
  __shared__ int gres[NBMAX];
  __shared__ int sscan[256];
  __shared__ __attribute__((aligned(16))) int2 buf[EB];
  int b = blockIdx.x;
  if (b >= NCB){   // W1 transpose+cvt
    int t2 = (b - NCB)*256 + threadIdx.x;
    if (t2 < 256*128){
      int k = t2 >> 7, n = t2 & 127;
      W1T[n*256 + k] = f2b(W1[t2]);
    }
    return;
  }
  int t = threadIdx.x;
  lh[t] = 0; lh[t+256] = 0;
  __syncthreads();
  int base = b*EB;
  #pragma unroll
  for (int k=0;k<EB/1024;k++){
    int idx = base + (k*256 + t)*4;
    if (idx < E){
      int4 d = *(const int4*)(dst + idx);
      atomicAdd(&lh[d.x>>BKT_BITS],1);
      atomicAdd(&lh[d.y>>BKT_BITS],1);
      atomicAdd(&lh[d.z>>BKT_BITS],1);
      atomicAdd(&lh[d.w>>BKT_BITS],1);
    }
  }
  __syncthreads();
  // exclusive scan of lh[0..512) (2 entries/thread)
  int i0 = 2*t, i1 = 2*t+1;
  int v0 = lh[i0], v1 = lh[i1];
  int tsum = v0+v1;
  sscan[t] = tsum; __syncthreads();
  for (int off=1; off<256; off<<=1){
    int v = (t>=off)? sscan[t-off]:0;
    __syncthreads();
    sscan[t]+=v;
    __syncthreads();
  }
  int run = sscan[t]-tsum;
  lofs[i0] = run;      lofs[i1] = run+v0;
  lcur[i0] = run;      lcur[i1] = run+v0;
  for (int i=t;i<NBMAX;i+=256)
    gres[i] = lh[i] ? (i*BSTRIDE + atomicAdd(&bcnt[i], lh[i])) : 0;
  __syncthreads();
  #pragma unroll
  for (int k=0;k<EB/1024;k++){
    int idx = base + (k*256 + t)*4;
    if (idx < E){
      int4 s4 = *(const int4*)(src + idx);
      int4 d4 = *(const int4*)(dst + idx);
      int p;
      p = atomicAdd(&lcur[d4.x>>BKT_BITS],1); buf[p] = make_int2(s4.x,d4.x);
      p = atomicAdd(&lcur[d4.y>>BKT_BITS],1); buf[p] = make_int2(s4.y,d4.y);
      p = atomicAdd(&lcur[d4.z>>BKT_BITS],1); buf[p] = make_int2(s4.z,d4.z);
      p = atomicAdd(&lcur[d4.w>>BKT_BITS],1); buf[p] = make_int2(s4.w,d4.w);
    }
  }
  __syncthreads();
  int total = E - base; if (total > EB) total = EB;
  for (int i=t; i<total; i+=256){
    int2 pr = buf[i];
    int bb = pr.y>>BKT_BITS;
    bins[gres[bb] + (i - lofs[bb])] = ((unsigned)pr.x << BKT_BITS) | (unsigned)(pr.y & (BKT-1));
  }
}

// ---------------- K2: bfill || gemm1, parity-interleaved, RACE-FREE ----------------
// R12 failure root-cause: gemm1's epilogue read dinv (written by bfill in the same
// kernel) -> race when interleaved. Fix: gemm1 now writes UNSCALED h1b (no dinv use);
// agg1 applies dinv[src] at gather time. The two branches share no data:
//   bfill: bins,bcnt -> rowptr,dinv,col      gemm1: X,w1t -> h1b

__global__ __launch_bounds__(512)
void bfill_gemm1(const unsigned int* __restrict__ bins, const int* __restrict__ bcnt,
                 int* __restrict__ rowptr, float* __restrict__ dinv, int* __restrict__ col,
                 const float* __restrict__ X, const unsigned short* __restrict__ W1T,
                 unsigned short* __restrict__ H1B, int N, int NB){
  __shared__ __attribute__((aligned(16))) char smem[64*512*2];   // 64KB union
  const int t = threadIdx.x;
  const int half = blockIdx.x >> 1;

  if (blockIdx.x & 1){
    // ---- bfill branch (odd blocks; bucket = half) ----
    const int b = half;
    int* dcnt  = (int*)smem;
    int* rp    = dcnt + 256;
    int* cur   = rp + 256;
    int* sscan = cur + 256;
    int* sboff = sscan + 256;
    if (t == 0) *sboff = 0;
    if (t < 256) dcnt[t] = 0;
    __syncthreads();
    int partial = 0;
    for (int j=t; j<b; j+=512) partial += bcnt[j];
    if (partial) atomicAdd(sboff, partial);
    __syncthreads();
    int s = *sboff, cnt = bcnt[b];
    const unsigned int* mybins = bins + (size_t)b*BSTRIDE;
    for (int i=t;i<cnt;i+=512) atomicAdd(&dcnt[mybins[i] & (BKT-1)], 1);
    __syncthreads();
    int base = b<<BKT_BITS;
    int node = base + t;
    int d0 = 0, n0 = 0;
    if (t < 256){
      d0 = dcnt[t];
      n0 = (node < N) ? d0+1 : 0;
      sscan[t] = n0;
    }
    __syncthreads();
    for (int off=1; off<256; off<<=1){
      int v = 0;
      if (t < 256 && t >= off) v = sscan[t-off];
      __syncthreads();
      if (t < 256) sscan[t] += v;
      __syncthreads();
    }
    if (t < 256){
      int run = sscan[t]-n0;
      int rp0 = s + base + run;   // prior buckets: s edges + base self-loops
      rp[t] = rp0; cur[t] = 0;
      if (node < N){
        rowptr[node] = rp0;
        dinv[node] = rsqrtf((float)(d0+1));
        col[rp0 + d0] = node;               // self-loop last (slot disjoint from fill)
        if (node == N-1) rowptr[N] = rp0 + d0 + 1;
      }
    }
    __syncthreads();
    for (int i=t;i<cnt;i+=512){
      unsigned pk = mybins[i];
      int ln = pk & (BKT-1);
      int slot = atomicAdd(&cur[ln], 1);
      col[rp[ln] + slot] = (int)(pk >> BKT_BITS);
    }
    return;
  }

  // ---- gemm1 v5 branch (even blocks; bid = half): UNSCALED h1b, no dinv ----
  unsigned short* wsh = (unsigned short*)smem;
  const int bid = half;
  const int wave = t >> 6, lane = t & 63;
  const int quad = lane >> 4, l16 = lane & 15;
  const int M = N;

  #pragma unroll
  for (int f0=0; f0<64; f0+=8){
    int f = f0 + wave;
    int ct = f >> 3, ts = f & 7;
    uint4 v = *(const uint4*)(W1T + (ct*16 + l16)*256 + ts*32 + quad*8);
    *(uint4*)(wsh + f*512 + lane*8) = v;
  }
  __syncthreads();

  const int row0 = bid * 256 + wave * 32;
  int rA = row0 + l16;
  int rB = rA + 16;
  int rAc = (rA < M) ? rA : (M-1);
  int rBc = (rB < M) ? rB : (M-1);
  const float* xA = X + (size_t)rAc*256 + quad*8;
  const float* xB = X + (size_t)rBc*256 + quad*8;

  f32x4 acc[2][8];
  #pragma unroll
  for (int i=0;i<2;i++)
    #pragma unroll
    for (int j=0;j<8;j++) acc[i][j] = (f32x4){0.f,0.f,0.f,0.f};

  float4 pf[2][4];
  #pragma unroll
  for (int s=0;s<2;s++){
    pf[s][0] = *(const float4*)(xA + s*32);
    pf[s][1] = *(const float4*)(xA + s*32 + 4);
    pf[s][2] = *(const float4*)(xB + s*32);
    pf[s][3] = *(const float4*)(xB + s*32 + 4);
  }

  #pragma unroll
  for (int tt=0; tt<8; tt++){
    const int cur2 = tt & 1;
    union { bf16x8 v; unsigned u[4]; } fa, fb;
    fa.u[0] = pkbf(pf[cur2][0].x, pf[cur2][0].y);
    fa.u[1] = pkbf(pf[cur2][0].z, pf[cur2][0].w);
    fa.u[2] = pkbf(pf[cur2][1].x, pf[cur2][1].y);
    fa.u[3] = pkbf(pf[cur2][1].z, pf[cur2][1].w);
    fb.u[0] = pkbf(pf[cur2][2].x, pf[cur2][2].y);
    fb.u[1] = pkbf(pf[cur2][2].z, pf[cur2][2].w);
    fb.u[2] = pkbf(pf[cur2][3].x, pf[cur2][3].y);
    fb.u[3] = pkbf(pf[cur2][3].z, pf[cur2][3].w);
    if (tt < 6){
      pf[cur2][0] = *(const float4*)(xA + (tt+2)*32);
      pf[cur2][1] = *(const float4*)(xA + (tt+2)*32 + 4);
      pf[cur2][2] = *(const float4*)(xB + (tt+2)*32);
      pf[cur2][3] = *(const float4*)(xB + (tt+2)*32 + 4);
    }
    #pragma unroll
    for (int ct=0; ct<8; ct++){
      bf16x8 bf = *(const bf16x8*)(wsh + (ct*8 + tt)*512 + lane*8);
      acc[0][ct] = __builtin_amdgcn_mfma_f32_16x16x32_bf16(fa.v, bf, acc[0][ct], 0, 0, 0);
      acc[1][ct] = __builtin_amdgcn_mfma_f32_16x16x32_bf16(fb.v, bf, acc[1][ct], 0, 0, 0);
    }
  }

  #pragma unroll
  for (int rt=0; rt<2; rt++){
    int rbase = row0 + rt*16 + quad*4;
    #pragma unroll
    for (int rg=0; rg<4; rg++){
      int grow = rbase + rg;
      if (grow < M){
        #pragma unroll
        for (int ct=0; ct<8; ct++)
          H1B[(size_t)grow*128 + ct*16 + l16] = f2b(acc[rt][ct][rg]);
      }
    }
  }
}

// ---------------- agg1: gather with per-edge dinv[src] scaling ----------------
// h1b is unscaled; each edge's row is scaled by dinv[c] via FMA (same VALU count
// as before — adds became fmas). dinv[c]: 16 lanes load the same address -> one
// broadcast request per edge group.

__device__ inline void acc8s(float* a, uint4 u, float v){
  a[0]=fmaf(v,b2f_lo(u.x),a[0]); a[1]=fmaf(v,b2f_hi(u.x),a[1]);
  a[2]=fmaf(v,b2f_lo(u.y),a[2]); a[3]=fmaf(v,b2f_hi(u.y),a[3]);
  a[4]=fmaf(v,b2f_lo(u.z),a[4]); a[5]=fmaf(v,b2f_hi(u.z),a[5]);
  a[6]=fmaf(v,b2f_lo(u.w),a[6]); a[7]=fmaf(v,b2f_hi(u.w),a[7]);
}

__global__ __launch_bounds__(256)
void agg1_kernel(const unsigned short* __restrict__ H1B, const int* __restrict__ rowptr,
                 const int* __restrict__ col, const float* __restrict__ dinv,
                 const float* __restrict__ b1, unsigned int* __restrict__ R1B, int N){
  int node = blockIdx.x * 4 + (threadIdx.x >> 6);
  int lane = threadIdx.x & 63;
  int g   = lane >> 4;    // edge sub-group 0..3
  int l16 = lane & 15;    // 16B chunk within the 256B row
  if (node >= N) return;
  int s = rowptr[node], e = rowptr[node+1];
  float a[8];
  #pragma unroll
  for (int k=0;k<8;k++) a[k]=0.f;
  const char* hbase = (const char*)H1B + l16*16;
  int j = s;
  for (; j+15 < e; j+=16){
    int c0 = col[j+g], c1 = col[j+4+g], c2 = col[j+8+g], c3 = col[j+12+g];
    uint4 u0 = *(const uint4*)(hbase + (((unsigned)c0) << 8));
    uint4 u1 = *(const uint4*)(hbase + (((unsigned)c1) << 8));
    uint4 u2 = *(const uint4*)(hbase + (((unsigned)c2) << 8));
    uint4 u3 = *(const uint4*)(hbase + (((unsigned)c3) << 8));
    float v0 = dinv[c0], v1 = dinv[c1], v2 = dinv[c2], v3 = dinv[c3];
    acc8s(a, u0, v0); acc8s(a, u1, v1); acc8s(a, u2, v2); acc8s(a, u3, v3);
  }
  for (; j+7 < e; j+=8){
    int c0 = col[j+g], c1 = col[j+4+g];
    uint4 u0 = *(const uint4*)(hbase + (((unsigned)c0) << 8));
    uint4 u1 = *(const uint4*)(hbase + (((unsigned)c1) << 8));
    float v0 = dinv[c0], v1 = dinv[c1];
    acc8s(a, u0, v0); acc8s(a, u1, v1);
  }
  {
    int rem = e - j;   // 0..7
    if (g < rem){
      int c0 = col[j+g];
      uint4 u0 = *(const uint4*)(hbase + (((unsigned)c0) << 8));
      acc8s(a, u0, dinv[c0]);
    }
    if (g+4 < rem){
      int c1 = col[j+4+g];
      uint4 u1 = *(const uint4*)(hbase + (((unsigned)c1) << 8));
      acc8s(a, u1, dinv[c1]);
    }
  }
  #pragma unroll
  for (int k=0;k<8;k++){
    a[k] += __shfl_xor(a[k], 16);
    a[k] += __shfl_xor(a[k], 32);
  }
  if (g == 0){
    float dv = dinv[node];
    float4 bl = *(const float4*)(b1 + l16*8);
    float4 bh = *(const float4*)(b1 + l16*8 + 4);
    float f0, f1;
    unsigned int o0, o1, o2, o3;
    f0 = fmaxf(dv*a[0] + bl.x, 0.f); f1 = fmaxf(dv*a[1] + bl.y, 0.f);
    o0 = (unsigned)f2b(f0) | ((unsigned)f2b(f1) << 16);
    f0 = fmaxf(dv*a[2] + bl.z, 0.f); f1 = fmaxf(dv*a[3] + bl.w, 0.f);
    o1 = (unsigned)f2b(f0) | ((unsigned)f2b(f1) << 16);
    f0 = fmaxf(dv*a[4] + bh.x, 0.f); f1 = fmaxf(dv*a[5] + bh.y, 0.f);
    o2 = (unsigned)f2b(f0) | ((unsigned)f2b(f1) << 16);
    f0 = fmaxf(dv*a[6] + bh.z, 0.f); f1 = fmaxf(dv*a[7] + bh.w, 0.f);
    o3 = (unsigned)f2b(f0) | ((unsigned)f2b(f1) << 16);
    *(uint4*)(R1B + (size_t)node*64 + l16*4) = make_uint4(o0, o1, o2, o3);
  }
}

// ---------------- GEMM2: fully unrolled k-loop (16 uint4 loads in flight) ----------------
// padding dwords [5..7] zeroed so agg2's wide 8-dword row loads read zeros.

__global__ __launch_bounds__(256)
void gemm2_kernel(const unsigned int* __restrict__ R1B, const float* __restrict__ W2,
                  const float* __restrict__ dinv, unsigned int* __restrict__ H2B, int M){
  __shared__ float w2s[128*10];
  for (int i = threadIdx.x; i < 128*10; i += blockDim.x) w2s[i] = W2[i];
  __syncthreads();
  int r = blockIdx.x*blockDim.x + threadIdx.x;
  if (r >= M) return;
  float acc[10];
  #pragma unroll
  for (int c=0;c<10;c++) acc[c] = 0.f;
  const unsigned int* row = R1B + (size_t)r*64;
  #pragma unroll
  for (int k=0;k<64;k+=4){
    uint4 u = *(const uint4*)(row + k);
    float f0 = b2f_lo(u.x), f1 = b2f_hi(u.x);
    float f2 = b2f_lo(u.y), f3 = b2f_hi(u.y);
    float f4 = b2f_lo(u.z), f5 = b2f_hi(u.z);
    float f6 = b2f_lo(u.w), f7 = b2f_hi(u.w);
    #pragma unroll
    for (int c=0;c<10;c++){
      acc[c] += f0*w2s[(2*k+0)*10+c] + f1*w2s[(2*k+1)*10+c]
              + f2*w2s[(2*k+2)*10+c] + f3*w2s[(2*k+3)*10+c]
              + f4*w2s[(2*k+4)*10+c] + f5*w2s[(2*k+5)*10+c]
              + f6*w2s[(2*k+6)*10+c] + f7*w2s[(2*k+7)*10+c];
    }
  }
  float dv = dinv[r];
  unsigned int p[5];
  #pragma unroll
  for (int c=0;c<5;c++)
    p[c] = (unsigned)f2b(dv*acc[2*c]) | ((unsigned)f2b(dv*acc[2*c+1]) << 16);
  unsigned int* op = H2B + (size_t)r*8;
  *(uint4*)op = make_uint4(p[0],p[1],p[2],p[3]);
  *(uint4*)(op+4) = make_uint4(p[4],0u,0u,0u);
}

// ---------------- agg2 + bias + log_softmax: 16 lanes/node, 4 gather chains ----------------

__global__ __launch_bounds__(256)
void agg2_softmax_kernel(const unsigned int* __restrict__ H2B, const int* __restrict__ rowptr,
                         const int* __restrict__ col, const float* __restrict__ dinv,
                         const float* __restrict__ b2, float* __restrict__ out, int N){
  int tid = threadIdx.x;
  int node = blockIdx.x * 16 + (tid >> 4);
  int l16 = tid & 15;
  int g2 = l16 >> 3;      // edge sub-group 0..1
  int l8 = l16 & 7;       // dword slot within 32B row
  if (node >= N) return;
  int s = rowptr[node], e = rowptr[node+1];
  float aLo = 0.f, aHi = 0.f, bLo = 0.f, bHi = 0.f;
  float cLo = 0.f, cHi = 0.f, dLo = 0.f, dHi = 0.f;
  const unsigned int* hb = H2B + l8;
  int j = s;
  // 8 edges/iter: 4 independent gather chains per lane
  for (; j+7 < e; j += 8){
    unsigned u0 = hb[(size_t)col[j+g2]*8];
    unsigned u1 = hb[(size_t)col[j+2+g2]*8];
    unsigned u2 = hb[(size_t)col[j+4+g2]*8];
    unsigned u3 = hb[(size_t)col[j+6+g2]*8];
    aLo += b2f_lo(u0); aHi += b2f_hi(u0);
    bLo += b2f_lo(u1); bHi += b2f_hi(u1);
    cLo += b2f_lo(u2); cHi += b2f_hi(u2);
    dLo += b2f_lo(u3); dHi += b2f_hi(u3);
  }
  for (; j+3 < e; j += 4){
    unsigned u0 = hb[(size_t)col[j+g2]*8];
    unsigned u1 = hb[(size_t)col[j+2+g2]*8];
    aLo += b2f_lo(u0); aHi += b2f_hi(u0);
    bLo += b2f_lo(u1); bHi += b2f_hi(u1);
  }
  for (; j+1 < e; j += 2){
    unsigned u0 = hb[(size_t)col[j+g2]*8];
    aLo += b2f_lo(u0); aHi += b2f_hi(u0);
  }
  if (j < e && g2 == 0){
    unsigned u0 = hb[(size_t)col[j]*8];
    aLo += b2f_lo(u0); aHi += b2f_hi(u0);
  }
  aLo += bLo + cLo + dLo; aHi += bHi + cHi + dHi;
  aLo += __shfl_xor(aLo, 8);
  aHi += __shfl_xor(aHi, 8);
  float dv = dinv[node];
  float2 bb = (l8 < 5) ? *(const float2*)(b2 + 2*l8) : make_float2(0.f, 0.f);
  float c0 = (l8 < 5) ? (dv*aLo + bb.x) : -1e30f;
  float c1 = (l8 < 5) ? (dv*aHi + bb.y) : -1e30f;
  float m = fmaxf(c0, c1);
  m = fmaxf(m, __shfl_xor(m, 1));
  m = fmaxf(m, __shfl_xor(m, 2));
  m = fmaxf(m, __shfl_xor(m, 4));
  float ex = (l8 < 5) ? (expf(c0 - m) + expf(c1 - m)) : 0.f;
  ex += __shfl_xor(ex, 1);
  ex += __shfl_xor(ex, 2);
  ex += __shfl_xor(ex, 4);
  float lg = m + logf(ex);
  if (l8 < 5 && g2 == 0)
    *(float2*)(out + (size_t)node*10 + 2*l8) = make_float2(c0 - lg, c1 - lg);
}

// ---------------- launch ----------------

extern "C" void kernel_launch(void* const* d_in, const int* in_sizes, int n_in,
                              void* d_out, int out_size, void* d_ws, size_t ws_size,
                              hipStream_t stream){
  const float* x    = (const float*)d_in[0];
  const int*   ei   = (const int*)d_in[1];
  const float* W1   = (const float*)d_in[2];
  const float* b1   = (const float*)d_in[3];
  const float* W2   = (const float*)d_in[4];
  const float* b2   = (const float*)d_in[5];
  float* out = (float*)d_out;

  const int N = in_sizes[0] / 256;   // 100000
  const int E = in_sizes[1] / 2;     // 1600000
  const int NNZ = E + N;
  const int* src = ei;
  const int* dst = ei + E;
  const int NB = (N + BKT - 1) >> BKT_BITS;   // 391 buckets
  const int WB = 128;                         // wcvt tail blocks
  const int GB = (N + 255) / 256;             // 391 gemm1 blocks (== NB, interleave requires)

  char* ws = (char*)d_ws;
  size_t off = 0;
  auto alloc = [&](size_t bytes)->char*{
    char* p = ws + off;
    off = (off + bytes + 255) & ~(size_t)255;
    return p;
  };
  int*   bcnt   = (int*)  alloc((size_t)NBMAX*4);   // zeroed; reservation + final counts
  float* dinv   = (float*)alloc((size_t)N*4);
  int*   rowptr = (int*)  alloc((size_t)(N+1)*4);
  unsigned int* bins = (unsigned int*)alloc((size_t)NB*BSTRIDE*4);
  int*   col    = (int*)  alloc((size_t)NNZ*4);
  unsigned short* w1t = (unsigned short*)alloc((size_t)128*256*2);
  unsigned short* h1b = (unsigned short*)alloc((size_t)N*128*2);
  unsigned int*   r1b = (unsigned int*)  alloc((size_t)N*64*4);
  unsigned int*   h2b = (unsigned int*)  alloc((size_t)N*8*4);
  (void)ws_size;

  hipMemsetAsync(bcnt, 0, (size_t)NBMAX*4, stream);

  const int NCB = (E + EB - 1) / EB;   // 782 bin blocks

  binc_wcvt<<<NCB + WB, 256, 0, stream>>>(src, dst, bcnt, bins, W1, w1t, E, NCB);
  bfill_gemm1<<<NB + GB, 512, 0, stream>>>(bins, bcnt, rowptr, dinv, col, x, w1t, h1b, N, NB);

  agg1_kernel<<<(N+3)/4, 256, 0, stream>>>(h1b, rowptr, col, dinv, b1, r1b, N);
  gemm2_kernel<<<(N+BLK-1)/BLK, BLK, 0, stream>>>(r1b, W2, dinv, h2b, N);
  agg2_softmax_kernel<<<(N+15)/16, BLK, 0, stream>>>(h2b, rowptr, col, dinv, b2, out, N);
}